// Round 8
// baseline (27.071 us; speedup 1.0000x reference)
//
#include <hip/hip_runtime.h>

// DetectionLayer (Mask R-CNN style), MI355X. B=8, N=1000 ROIs, C=81.
// out: (B, 100, 6) float32 = [y1,x1,y2,x2,class_id,score]
//
// R8: barrier-count + gather-latency round.
//  - ping-pong bitonic LDS buffers: 1 barrier per cross-wave stage (was 2)
//  - cls packed into sort key (tid<<7|cls), boxes preloaded to LDS pre-sort:
//    post-sort gather is one LDS read; ssc/scls arrays and the random global
//    gather deleted; score/cls recovered from the key at emit
//  - cmask[chunk][class] built ONCE before the NMS loop (dead-leader bits
//    are filtered by the alive-mask AND): 1 barrier per chunk (was 3)

#define NROI 1000
#define NCLS 81
#define MAXI 100
#define PAD  1024            // per-image slab stride in workspace
#define BLK  1024
#define NW   (BLK / 64)
#define MIN_CONF 0.7f
#define NMS_THR  0.3f

typedef float f32x4u __attribute__((ext_vector_type(4), aligned(4)));
typedef unsigned long long u64;

__device__ __forceinline__ u64 shfl_xor_u64(u64 v, int m) {
  unsigned lo = (unsigned)__shfl_xor((int)(unsigned)(v & 0xFFFFFFFFull), m, 64);
  unsigned hi = (unsigned)__shfl_xor((int)(unsigned)(v >> 32), m, 64);
  return (((u64)hi) << 32) | lo;
}

// ---------------- kernel 1: per-ROI refine (widely parallel) ----------------
__global__ __launch_bounds__(64) void refine_kernel(
    const float* __restrict__ rois,    // B*N*4
    const float* __restrict__ probs,   // B*N*C
    const float* __restrict__ deltas,  // B*N*C*4
    const float* __restrict__ meta,    // B*meta_stride
    float4* __restrict__ ws_box,       // [B*PAD]
    float2* __restrict__ ws_aux,       // [B*PAD]  (score, cls)
    int meta_stride)
{
  const int b   = blockIdx.x >> 4;                  // 16 blocks per image
  const int roi = ((blockIdx.x & 15) << 6) + threadIdx.x;
  if (roi >= NROI) return;

  const float* p = probs + ((size_t)b * NROI + roi) * NCLS;
  float best = p[0];
  int   bc = 0;
  for (int c0 = 1; c0 < NCLS; c0 += 4) {            // 81 = 1 + 20*4, exact
    f32x4u v = *(const f32x4u*)(p + c0);
#pragma unroll
    for (int e = 0; e < 4; ++e) {
      float f = v[e];
      if (f > best) { best = f; bc = c0 + e; }      // strict > => first max
    }
  }

  const float4 dd = *(const float4*)(deltas + (((size_t)b * NROI + roi) * NCLS + bc) * 4);
  const float4 rr = *(const float4*)(rois + ((size_t)b * NROI + roi) * 4);

  float hh = rr.z - rr.x, ww = rr.w - rr.y;
  float cy = rr.x + 0.5f * hh + (dd.x * 0.1f) * hh;
  float cx = rr.y + 0.5f * ww + (dd.y * 0.1f) * ww;
  hh *= expf(dd.z * 0.2f);
  ww *= expf(dd.w * 0.2f);
  float ny1 = cy - 0.5f * hh, nx1 = cx - 0.5f * ww;
  float ny2 = cy + 0.5f * hh, nx2 = cx + 0.5f * ww;

  float H = meta[4], W = meta[5];                   // image_meta[0, 4:7]
  float sy = H - 1.0f, sx = W - 1.0f;
  const float* m = meta + (size_t)b * meta_stride;
  float wy1 = m[7] / sy, wx1 = m[8] / sx;
  float wy2 = (m[9] - 1.0f) / sy, wx2 = (m[10] - 1.0f) / sx;

  float4 bb;
  bb.x = fminf(fmaxf(ny1, wy1), wy2);
  bb.y = fminf(fmaxf(nx1, wx1), wx2);
  bb.z = fminf(fmaxf(ny2, wy1), wy2);
  bb.w = fminf(fmaxf(nx2, wx1), wx2);

  bool valid = (bc > 0) && (best >= MIN_CONF);
  float score = valid ? best : -1.0f;

  ws_box[(size_t)b * PAD + roi] = bb;
  ws_aux[(size_t)b * PAD + roi] = make_float2(score, (float)bc);
}

// ---------------- kernel 2: sort + NMS + emit (one block per image) ---------
__global__ __launch_bounds__(BLK) void sortnms_kernel(
    const float4* __restrict__ ws_box,
    const float2* __restrict__ ws_aux,
    float* __restrict__ out)
{
  const int b    = blockIdx.x;
  const int tid  = threadIdx.x;
  const int lane = tid & 63;
  const int wv   = tid >> 6;

  __shared__ u64    skeyA[BLK], skeyB[BLK];  // ping-pong bitonic buffers
  __shared__ float4 u_box[NROI];             // boxes in ORIGINAL order
  __shared__ float4 sbox[NROI];              // boxes in SORTED order ([0,V))
  __shared__ u64    cmask[NW][NCLS];         // chunk -> class -> leader lanes
  __shared__ u64    s_alive[NW];             // per-chunk resolved alive mask
  __shared__ int    wcnt[NW];

  // ---- zero this image's output (d_out poisoned, not re-poisoned)
  for (int k = tid; k < MAXI * 6; k += BLK)
    out[(size_t)b * (MAXI * 6) + k] = 0.0f;

  // ---- coalesced loads: score/cls (key build) + box preload into LDS
  float sc = -1.0f;
  int   cls = 0;
  if (tid < NROI) {
    float2 a = ws_aux[(size_t)b * PAD + tid];
    sc  = a.x;
    cls = (int)a.y;
    u_box[tid] = ws_box[(size_t)b * PAD + tid];
  }
  const bool valid = sc > -0.5f;

  // ---- stable compaction of valid entries (order-preserving in tid)
  u64 vb = __ballot(valid);
  if (lane == 0) wcnt[wv] = (int)__popcll(vb);
  __syncthreads();                           // b1: wcnt + u_box visible
  int V = 0, cbase0 = 0;
  for (int w = 0; w < NW; ++w) {
    int c = wcnt[w];
    if (w < wv) cbase0 += c;
    V += c;
  }
  // disjoint writes: valid keys -> slots [0,V), pad -> [V,BLK)
  if (valid) {
    int slot = cbase0 + (int)__popcll(vb & ((1ull << (unsigned)lane) - 1ull));
    unsigned bits = __float_as_uint(sc);
    unsigned ord  = bits | 0x80000000u;      // sc > 0 always here
    // key = (~ord)<<32 | tid<<7 | cls : ascending == stable descending
    // argsort on score (ties -> lower tid; cls in low bits can't flip order)
    skeyA[slot] = (((u64)(~ord)) << 32) | ((unsigned)tid << 7) | (unsigned)cls;
  }
  if (tid >= V) skeyA[tid] = 0xFFFFFFFFFFFFFFFFull;  // padding sorts last
  // clear cmask while we're between barriers (untouched until post-sort)
  {
    u64* cf = &cmask[0][0];
    for (int i = tid; i < NW * NCLS; i += BLK) cf[i] = 0ull;
  }
  __syncthreads();                           // b2: keys + cmask-clear ready

  // ---- hybrid bitonic sort of P = next_pow2(max(V,64)) compacted keys
  int P = 64;
  while (P < V) P <<= 1;
  const bool insort = tid < P;               // wave-uniform

  u64 key = skeyA[tid];
  int ldst = 1;                              // skeyA holds stage-0 content
  for (int k = 2; k <= P; k <<= 1) {
    for (int j = k >> 1; j > 0; j >>= 1) {
      const bool takeMin = (((tid & j) == 0) == ((tid & k) == 0));
      if (j >= 64) {                         // cross-wave via ping-pong LDS
        u64* buf = (ldst & 1) ? skeyB : skeyA;
        if (insort) buf[tid] = key;
        __syncthreads();                     // one barrier per stage
        if (insort) {
          u64 other = buf[tid ^ j];
          key = (takeMin ? (other < key) : (other > key)) ? other : key;
        }
        ++ldst;
      } else if (insort) {                   // in-wave via shfl_xor
        u64 other = shfl_xor_u64(key, j);
        key = (takeMin ? (other < key) : (other > key)) ? other : key;
      }
    }
  }

  // ---- gather (LDS only) + cmask build
  bool   mykeep = tid < V;
  float4 jb = make_float4(0.f, 0.f, 0.f, 0.f);
  float  jarea = 0.f;
  int    jcls = -1;
  if (mykeep) {
    int oid = (int)((key >> 7) & 0x3FFull);  // original index
    jcls = (int)(key & 0x7Full);
    jb = u_box[oid];
    jarea = (jb.z - jb.x) * (jb.w - jb.y);
    sbox[tid] = jb;
    atomicOr(&cmask[wv][jcls], 1ull << (unsigned)lane);
  }
  __syncthreads();                           // b3: sbox + cmask visible

  // ---- class-masked chunked greedy NMS (== sequential greedy exactly)
  int kc = 0;
  const int nchunks = (V + 63) >> 6;
  for (int c = 0; c < nchunks; ++c) {
    const int cb = c << 6;

    // jsup bit l: chunk entry l (same class) suppresses me if l is kept.
    // cmask may contain leaders later killed: harmless — resolve starts from
    // ballot(mykeep) and cross-wave kills are ANDed with the alive mask.
    u64 jsup = 0ull;
    if (mykeep && wv >= c) {
      u64 m = cmask[c][jcls];
      if (wv == c) m &= (1ull << (unsigned)lane) - 1ull;   // earlier lanes only
      while (m) {
        int l = __ffsll((long long)m) - 1;
        m &= m - 1;
        float4 lb = sbox[cb + l];            // uniform addr -> LDS broadcast
        float la = (lb.z - lb.x) * (lb.w - lb.y);
        float iy1 = fmaxf(lb.x, jb.x), ix1 = fmaxf(lb.y, jb.y);
        float iy2 = fminf(lb.z, jb.z), ix2 = fminf(lb.w, jb.w);
        float inter = fmaxf(iy2 - iy1, 0.f) * fmaxf(ix2 - ix1, 0.f);
        if (inter > NMS_THR * fmaxf(la + jarea - inter, 1e-10f))
          jsup |= (1ull << (unsigned)l);
      }
    }

    if (wv == c) {                           // greedy resolve, set bits only
      u64 aliveW = __ballot(mykeep);
      u64 rem = aliveW;
      while (rem) {
        int l = __ffsll((long long)rem) - 1;
        rem &= ~(1ull << (unsigned)l);
        u64 kill = __ballot((int)((jsup >> (unsigned)l) & 1ull));
        aliveW &= ~kill;                     // jsup bits only at lanes > l here
        rem    &= ~kill;
      }
      mykeep = ((aliveW >> (unsigned)lane) & 1ull) != 0;
      if (lane == 0) s_alive[c] = aliveW;
    }
    __syncthreads();                         // one barrier per chunk
    const u64 alive = s_alive[c];
    if (wv > c && (jsup & alive)) mykeep = false;
    kc += (int)__popcll(alive);
    // Output = first MAXI kept in sorted order; once MAXI are finalized,
    // later suppressions cannot change the output (== full NMS + top_k).
    if (kc >= MAXI) break;
  }

  // ---- ballot-scan compaction + emit.
  // Stale mykeep=1 threads (unprocessed chunks) get slot >= kc >= MAXI.
  u64 bm = __ballot((int)mykeep);
  if (lane == 0) wcnt[wv] = (int)__popcll(bm);
  __syncthreads();
  if (mykeep) {
    int base2 = 0;
    for (int q = 0; q < wv; ++q) base2 += wcnt[q];
    int slot = base2 + (int)__popcll(bm & ((1ull << (unsigned)lane) - 1ull));
    if (slot < MAXI) {
      unsigned ordhi = ~(unsigned)(key >> 32);
      float score = __uint_as_float(ordhi & 0x7FFFFFFFu);
      float* o = out + ((size_t)b * MAXI + slot) * 6;
      o[0] = jb.x; o[1] = jb.y; o[2] = jb.z; o[3] = jb.w;
      o[4] = (float)jcls;
      o[5] = score;
    }
  }
}

extern "C" void kernel_launch(void* const* d_in, const int* in_sizes, int n_in,
                              void* d_out, int out_size, void* d_ws, size_t ws_size,
                              hipStream_t stream) {
  const float* rois   = (const float*)d_in[0];
  const float* probs  = (const float*)d_in[1];
  const float* deltas = (const float*)d_in[2];
  const float* meta   = (const float*)d_in[3];
  float* out = (float*)d_out;

  const int nb = in_sizes[0] / (NROI * 4);       // = 8 images
  const int meta_stride = in_sizes[3] / nb;      // = 93 floats per image

  float4* ws_box = (float4*)d_ws;                              // nb*PAD*16 B
  float2* ws_aux = (float2*)((char*)d_ws + (size_t)nb * PAD * sizeof(float4));

  refine_kernel<<<nb * 16, 64, 0, stream>>>(rois, probs, deltas, meta,
                                            ws_box, ws_aux, meta_stride);
  sortnms_kernel<<<nb, BLK, 0, stream>>>(ws_box, ws_aux, out);
}